// Round 6
// baseline (155.476 us; speedup 1.0000x reference)
//
#include <hip/hip_runtime.h>

// B=8 images, G=32 gt/img, A=200000 anchors (B, A derived at launch).
#define G 32
#define APT 4               // anchors per thread (R3-proven config)
#define CHUNK (256 * APT)   // anchors per block = flag granularity for k3

// IoU must be bit-identical everywhere (exact == vs hi) and match numpy's
// unfused f32 arithmetic -> contraction off.
// NOTE: no `inter > 0` select — both areas are strictly positive in this
// problem (w,h >= 8), so uni > 0 always and inter==0 gives +0.0f exactly,
// bitwise equal to the reference's where(inter>0, inter/uni, 0).
__device__ __forceinline__ float iou_pre(float sum_area,
                                         float g0, float g1, float g2, float g3,
                                         float a0, float a1, float a2, float a3) {
#pragma clang fp contract(off)
    float ltx = fmaxf(g0, a0), lty = fmaxf(g1, a1);
    float rbx = fminf(g2, a2), rby = fminf(g3, a3);
    float wx = fmaxf(rbx - ltx, 0.0f), wy = fmaxf(rby - lty, 0.0f);
    float inter = wx * wy;
    float uni = sum_area - inter;
    return inter / uni;
}

__device__ __forceinline__ float centerness_fn(float4 an, float4 tb) {
#pragma clang fp contract(off)
    float cx = 0.5f * (an.x + an.z), cy = 0.5f * (an.y + an.w);
    float w = an.z - an.x, h = an.w - an.y;
    float d0 = (cx - tb.x) / w;
    float d1 = (tb.z - cx) / w;
    float d2 = (cy - tb.y) / h;
    float d3 = (tb.w - cy) / h;
    bool inb = (d0 >= 0.0f) && (d1 >= 0.0f) && (d2 >= 0.0f) && (d3 >= 0.0f);
    if (!inb) { d0 = d1 = d2 = d3 = 0.0f; }
    float prod = (fminf(d0, d1) / (fmaxf(d0, d1) + 1e-12f)) *
                 (fminf(d2, d3) / (fmaxf(d2, d3) + 1e-12f));
    return prod > 0.0f ? sqrtf(prod) : 0.0f;
}

// K1: gt-outer / anchors-in-registers inner (wave-uniform gt -> s_load; no LDS
// in hot loop). Writes final outputs (labels WITHOUT low-quality correction;
// k3 patches) + per-chunk per-gt max (blockmax). No atomics, no hi — k3
// derives hi from blockmax (bit-exact: fmaxf over the same value set).
__global__ __launch_bounds__(256) void k1_main(const float* __restrict__ gt,
                                               const float* __restrict__ anchors,
                                               float* __restrict__ out,
                                               float* __restrict__ blockmax,
                                               int A, int B) {
#pragma clang fp contract(off)
    __shared__ float4 s_gt[G];        // for epilogue indexed fetch only
    __shared__ float s_red[G * 4];
    const int c = blockIdx.x, b = blockIdx.y, t = threadIdx.x;
    if (t < G) s_gt[t] = ((const float4*)gt)[b * G + t];

    const float4* __restrict__ gt4 = (const float4*)gt;

    float4 an[APT];
    float aa[APT], best[APT];
    int bidx[APT];
    bool valid[APT];
    const int abase = c * CHUNK + t;
#pragma unroll
    for (int k = 0; k < APT; ++k) {
        int a = abase + k * 256;
        valid[k] = (a < A);
        int ac = valid[k] ? a : (A - 1);   // clamp: dup contributions are max-harmless
        an[k] = ((const float4*)anchors)[ac];
        aa[k] = (an[k].z - an[k].x) * (an[k].w - an[k].y);
        best[k] = -1.0f;
        bidx[k] = 0;
    }

    const int lane = t & 63, wid = t >> 6;

    for (int g = 0; g < G; ++g) {
        const float4 gb = gt4[b * G + g];   // uniform address -> s_load
        const float ag = (gb.z - gb.x) * (gb.w - gb.y);
        float v[APT];
#pragma unroll
        for (int k = 0; k < APT; ++k) {
            v[k] = iou_pre(ag + aa[k], gb.x, gb.y, gb.z, gb.w,
                           an[k].x, an[k].y, an[k].z, an[k].w);
            if (v[k] > best[k]) { best[k] = v[k]; bidx[k] = g; }  // strict '>': jnp.argmax tie-break
        }
        float lm = fmaxf(fmaxf(v[0], v[1]), fmaxf(v[2], v[3]));   // tree max
#pragma unroll
        for (int off = 32; off > 0; off >>= 1) lm = fmaxf(lm, __shfl_down(lm, off, 64));
        if (lane == 0) s_red[g * 4 + wid] = lm;
    }
    __syncthreads();
    if (t < G) {
        float v = fmaxf(fmaxf(s_red[t * 4 + 0], s_red[t * 4 + 1]),
                        fmaxf(s_red[t * 4 + 2], s_red[t * 4 + 3]));
        blockmax[(c * B + b) * G + t] = v;
    }

    const size_t BA = (size_t)B * (size_t)A;
    const size_t bA = (size_t)b * (size_t)A;
#pragma unroll
    for (int k = 0; k < APT; ++k) {
        if (!valid[k]) continue;
        const size_t o = bA + (size_t)(abase + k * 256);
        int gl = (best[k] >= 0.7f) ? 1 : ((best[k] >= 0.3f) ? -1 : 0);
        int ol = (best[k] >= 0.3f) ? 1 : ((best[k] >= 0.1f) ? -1 : 0);
        const float4 tb = s_gt[bidx[k]];
        float cen = centerness_fn(an[k], tb);
        if (ol == 0) cen = 0.0f;
        out[o] = (float)gl;
        ((float4*)(out + BA))[o] = tb;
        out[5 * BA + o] = (float)ol;
        out[6 * BA + o] = cen;
    }
}

// K3 (lite): low-quality patch. hi[b,g] is derived here as max over chunks of
// blockmax (bit-exact regardless of order). A chunk can contain an anchor
// with iou==hi[g] only if its blockmax[g]==hi[g] (iou<=chunkmax<=hi). ~85%
// of blocks exit on mask==0. Flagged blocks rescan ONLY the flagged gts
// (popcount ~1-2) with code bit-identical to k1; the matched box is read
// back from out (k1's argmax), only gl/ol/centerness are rewritten.
__global__ __launch_bounds__(256) void k3_patch(const float* __restrict__ gt,
                                                const float* __restrict__ anchors,
                                                const float* __restrict__ blockmax,
                                                float* __restrict__ out,
                                                int A, int B, int C) {
#pragma clang fp contract(off)
    __shared__ float4 s_gt[G];
    __shared__ float s_hi[G];
    __shared__ unsigned s_mask;
    const int c = blockIdx.x, b = blockIdx.y, t = threadIdx.x;
    const int BG = B * G;
    bool fl = false;
    if (t < G) {
        s_gt[t] = ((const float4*)gt)[b * G + t];
        float h = 0.0f;
        for (int cc = 0; cc < C; ++cc)
            h = fmaxf(h, blockmax[cc * BG + b * G + t]);   // L2-resident, ~25 KB/b
        s_hi[t] = h;
        fl = (blockmax[c * BG + b * G + t] == h);
    }
    unsigned long long m = __ballot(fl);
    if (t == 0) s_mask = (unsigned)(m & 0xffffffffull);
    __syncthreads();
    const unsigned mask0 = s_mask;
    if (mask0 == 0) return;

    const size_t BA = (size_t)B * (size_t)A;
    const size_t bA = (size_t)b * (size_t)A;
    const int abase = c * CHUNK + t;

#pragma unroll
    for (int k = 0; k < APT; ++k) {
        const int a = abase + k * 256;
        if (a >= A) continue;
        const float4 an = ((const float4*)anchors)[a];
        const float aa = (an.z - an.x) * (an.w - an.y);
        bool lq = false;
        unsigned mask = mask0;           // block-uniform loop, ~1-2 iterations
        while (mask) {
            const int g = __ffs(mask) - 1;
            mask &= mask - 1;
            const float4 gb = s_gt[g];
            const float ag = (gb.z - gb.x) * (gb.w - gb.y);
            const float v = iou_pre(ag + aa, gb.x, gb.y, gb.z, gb.w,
                                    an.x, an.y, an.z, an.w);
            lq |= (v == s_hi[g]);        // non-flagged g can never hit (v<=blockmax<hi)
        }
        if (lq) {
            const size_t o = bA + (size_t)a;
            const float4 tb = ((const float4*)(out + BA))[o];  // k1's matched box
            const float cen = centerness_fn(an, tb);           // ol=1 -> unmasked
            out[o] = 1.0f;
            out[5 * BA + o] = 1.0f;
            out[6 * BA + o] = cen;
        }
    }
}

extern "C" void kernel_launch(void* const* d_in, const int* in_sizes, int n_in,
                              void* d_out, int out_size, void* d_ws, size_t ws_size,
                              hipStream_t stream) {
    const float* gt = (const float*)d_in[0];       // [B, 32, 4] f32
    const float* anchors = (const float*)d_in[1];  // [A, 4] f32
    float* out = (float*)d_out;

    const int B = in_sizes[0] / (G * 4);
    const int A = in_sizes[1] / 4;
    const int C = (A + CHUNK - 1) / CHUNK;

    float* blockmax = (float*)d_ws;                  // C*B*G floats (~200 KB)

    k1_main<<<dim3(C, B), 256, 0, stream>>>(gt, anchors, out, blockmax, A, B);
    k3_patch<<<dim3(C, B), 256, 0, stream>>>(gt, anchors, blockmax, out, A, B, C);
}

// Round 7
// 119.798 us; speedup vs baseline: 1.2978x; 1.2978x over previous
//
#include <hip/hip_runtime.h>

// B=8 images, G=32 gt/img, A=200000 anchors (B, A derived at launch).
#define G 32
#define APT 4               // anchors per thread (R3/R5-proven config)
#define CHUNK (256 * APT)   // anchors per block = flag granularity for k3

// IoU: identical formula in k1/k3 -> bit-identical values (the == hi test
// and blockmax filter only need self-consistency, not correct rounding).
// Division replaced by v_rcp_f32 + mul (~1 ulp): discrete decisions vs the
// f64 reference (label thresholds, argmax ties) tolerate this — the exact-f32
// run already perturbed ~1 ulp vs f64 with zero flips (absmax 0.0039,
// continuous-only). No `inter > 0` select: areas strictly positive ->
// uni > 0, inter==0 gives +0.0f exactly.
__device__ __forceinline__ float iou_pre(float sum_area,
                                         float g0, float g1, float g2, float g3,
                                         float a0, float a1, float a2, float a3) {
#pragma clang fp contract(off)
    float ltx = fmaxf(g0, a0), lty = fmaxf(g1, a1);
    float rbx = fminf(g2, a2), rby = fminf(g3, a3);
    float wx = fmaxf(rbx - ltx, 0.0f), wy = fmaxf(rby - lty, 0.0f);
    float inter = wx * wy;
    float uni = sum_area - inter;
    return inter * __builtin_amdgcn_rcpf(uni);
}

// Epilogue centerness: exact divides (sign/zero decisions must be exact;
// runs once per anchor, cost negligible).
__device__ __forceinline__ float centerness_fn(float4 an, float4 tb) {
#pragma clang fp contract(off)
    float cx = 0.5f * (an.x + an.z), cy = 0.5f * (an.y + an.w);
    float w = an.z - an.x, h = an.w - an.y;
    float d0 = (cx - tb.x) / w;
    float d1 = (tb.z - cx) / w;
    float d2 = (cy - tb.y) / h;
    float d3 = (tb.w - cy) / h;
    bool inb = (d0 >= 0.0f) && (d1 >= 0.0f) && (d2 >= 0.0f) && (d3 >= 0.0f);
    if (!inb) { d0 = d1 = d2 = d3 = 0.0f; }
    float prod = (fminf(d0, d1) / (fmaxf(d0, d1) + 1e-12f)) *
                 (fminf(d2, d3) / (fmaxf(d2, d3) + 1e-12f));
    return prod > 0.0f ? sqrtf(prod) : 0.0f;
}

// K1: gt-outer / anchors-in-registers inner (wave-uniform gt -> s_load; no LDS
// in hot loop; g-loop unrolled x8 to batch s_loads). Writes final outputs
// (labels WITHOUT low-quality correction; k3 patches) + per-chunk per-gt max.
__global__ __launch_bounds__(256) void k1_main(const float* __restrict__ gt,
                                               const float* __restrict__ anchors,
                                               float* __restrict__ out,
                                               float* __restrict__ blockmax,
                                               int A, int B) {
#pragma clang fp contract(off)
    __shared__ float4 s_gt[G];        // for epilogue indexed fetch only
    __shared__ float s_red[G * 4];
    const int c = blockIdx.x, b = blockIdx.y, t = threadIdx.x;
    if (t < G) s_gt[t] = ((const float4*)gt)[b * G + t];

    const float4* __restrict__ gt4 = (const float4*)gt;

    float4 an[APT];
    float aa[APT], best[APT];
    int bidx[APT];
    bool valid[APT];
    const int abase = c * CHUNK + t;
#pragma unroll
    for (int k = 0; k < APT; ++k) {
        int a = abase + k * 256;
        valid[k] = (a < A);
        int ac = valid[k] ? a : (A - 1);   // clamp: dup contributions are max-harmless
        an[k] = ((const float4*)anchors)[ac];
        aa[k] = (an[k].z - an[k].x) * (an[k].w - an[k].y);
        best[k] = -1.0f;
        bidx[k] = 0;
    }

    const int lane = t & 63, wid = t >> 6;

#pragma unroll 8
    for (int g = 0; g < G; ++g) {
        const float4 gb = gt4[b * G + g];   // uniform address -> s_load, batched by unroll
        const float ag = (gb.z - gb.x) * (gb.w - gb.y);
        float v[APT];
#pragma unroll
        for (int k = 0; k < APT; ++k) {
            v[k] = iou_pre(ag + aa[k], gb.x, gb.y, gb.z, gb.w,
                           an[k].x, an[k].y, an[k].z, an[k].w);
            if (v[k] > best[k]) { best[k] = v[k]; bidx[k] = g; }  // strict '>': jnp.argmax tie-break
        }
        float lm = fmaxf(fmaxf(v[0], v[1]), fmaxf(v[2], v[3]));
#pragma unroll
        for (int off = 32; off > 0; off >>= 1) lm = fmaxf(lm, __shfl_down(lm, off, 64));
        if (lane == 0) s_red[g * 4 + wid] = lm;
    }
    __syncthreads();
    if (t < G) {
        float v = fmaxf(fmaxf(s_red[t * 4 + 0], s_red[t * 4 + 1]),
                        fmaxf(s_red[t * 4 + 2], s_red[t * 4 + 3]));
        blockmax[(c * B + b) * G + t] = v;
    }

    const size_t BA = (size_t)B * (size_t)A;
    const size_t bA = (size_t)b * (size_t)A;
#pragma unroll
    for (int k = 0; k < APT; ++k) {
        if (!valid[k]) continue;
        const size_t o = bA + (size_t)(abase + k * 256);
        int gl = (best[k] >= 0.7f) ? 1 : ((best[k] >= 0.3f) ? -1 : 0);
        int ol = (best[k] >= 0.3f) ? 1 : ((best[k] >= 0.1f) ? -1 : 0);
        const float4 tb = s_gt[bidx[k]];
        float cen = centerness_fn(an[k], tb);
        if (ol == 0) cen = 0.0f;
        out[o] = (float)gl;
        ((float4*)(out + BA))[o] = tb;
        out[5 * BA + o] = (float)ol;
        out[6 * BA + o] = cen;
    }
}

// K2: hi[bg] = max over C chunks of blockmax. One block (64 thr) per (b,g).
// Bit-exact: fmaxf over the same value set, any order.
__global__ void k2_reduce(const float* __restrict__ blockmax,
                          float* __restrict__ hi, int C, int BG) {
    const int bg = blockIdx.x, t = threadIdx.x;
    float v = 0.0f;
    for (int c = t; c < C; c += 64) v = fmaxf(v, blockmax[c * BG + bg]);
#pragma unroll
    for (int off = 32; off > 0; off >>= 1) v = fmaxf(v, __shfl_down(v, off, 64));
    if (t == 0) hi[bg] = v;
}

// K3 (lite): low-quality patch. A chunk can contain an anchor with
// iou==hi[g] only if its blockmax[g]==hi[g] (iou<=chunkmax<=hi, bit-exact).
// ~85% of blocks exit on mask==0. Flagged blocks rescan ONLY flagged gts
// (popcount ~1-2); matched box is read back from out (k1's argmax), only
// gl/ol/centerness rewritten for v==hi[g] lanes.
__global__ __launch_bounds__(256) void k3_patch(const float* __restrict__ gt,
                                                const float* __restrict__ anchors,
                                                const float* __restrict__ blockmax,
                                                const float* __restrict__ hi,
                                                float* __restrict__ out,
                                                int A, int B) {
#pragma clang fp contract(off)
    __shared__ float4 s_gt[G];
    __shared__ float s_hi[G];
    __shared__ unsigned s_mask;
    const int c = blockIdx.x, b = blockIdx.y, t = threadIdx.x;
    bool fl = false;
    if (t < G) {
        float h = hi[b * G + t];
        s_hi[t] = h;
        s_gt[t] = ((const float4*)gt)[b * G + t];
        fl = (blockmax[(c * B + b) * G + t] == h);
    }
    unsigned long long m = __ballot(fl);
    if (t == 0) s_mask = (unsigned)(m & 0xffffffffull);
    __syncthreads();
    const unsigned mask0 = s_mask;
    if (mask0 == 0) return;

    const size_t BA = (size_t)B * (size_t)A;
    const size_t bA = (size_t)b * (size_t)A;
    const int abase = c * CHUNK + t;

#pragma unroll
    for (int k = 0; k < APT; ++k) {
        const int a = abase + k * 256;
        if (a >= A) continue;
        const float4 an = ((const float4*)anchors)[a];
        const float aa = (an.z - an.x) * (an.w - an.y);
        bool lq = false;
        unsigned mask = mask0;           // block-uniform loop, ~1-2 iterations
        while (mask) {
            const int g = __ffs(mask) - 1;
            mask &= mask - 1;
            const float4 gb = s_gt[g];
            const float ag = (gb.z - gb.x) * (gb.w - gb.y);
            const float v = iou_pre(ag + aa, gb.x, gb.y, gb.z, gb.w,
                                    an.x, an.y, an.z, an.w);
            lq |= (v == s_hi[g]);        // non-flagged g can never hit (v<=blockmax<hi)
        }
        if (lq) {
            const size_t o = bA + (size_t)a;
            const float4 tb = ((const float4*)(out + BA))[o];  // k1's matched box
            const float cen = centerness_fn(an, tb);           // ol=1 -> unmasked
            out[o] = 1.0f;
            out[5 * BA + o] = 1.0f;
            out[6 * BA + o] = cen;
        }
    }
}

extern "C" void kernel_launch(void* const* d_in, const int* in_sizes, int n_in,
                              void* d_out, int out_size, void* d_ws, size_t ws_size,
                              hipStream_t stream) {
    const float* gt = (const float*)d_in[0];       // [B, 32, 4] f32
    const float* anchors = (const float*)d_in[1];  // [A, 4] f32
    float* out = (float*)d_out;

    const int B = in_sizes[0] / (G * 4);
    const int A = in_sizes[1] / 4;
    const int C = (A + CHUNK - 1) / CHUNK;
    const int BG = B * G;

    float* hi = (float*)d_ws;                        // BG floats (k2 fully overwrites)
    float* blockmax = (float*)((char*)d_ws + 1024);  // C*BG floats (~200 KB)

    k1_main<<<dim3(C, B), 256, 0, stream>>>(gt, anchors, out, blockmax, A, B);
    k2_reduce<<<BG, 64, 0, stream>>>(blockmax, hi, C, BG);
    k3_patch<<<dim3(C, B), 256, 0, stream>>>(gt, anchors, blockmax, hi, out, A, B);
}

// Round 8
// 112.838 us; speedup vs baseline: 1.3779x; 1.0617x over previous
//
#include <hip/hip_runtime.h>

// B=8 images, G=32 gt/img, A=200000 anchors (B, A derived at launch).
#define G 32
#define APT 4               // anchors per thread (R3/R5-proven config)
#define CHUNK (256 * APT)   // anchors per block = flag granularity for k3

// IoU: identical formula in k1/k3 -> bit-identical values (the == hi test
// and blockmax filter only need self-consistency, not correct rounding).
// Division replaced by v_rcp_f32 + mul (~1 ulp): R7 validated zero discrete
// flips (absmax 0.0039, continuous-only). No `inter > 0` select: areas
// strictly positive -> uni > 0, inter==0 gives +0.0f exactly.
__device__ __forceinline__ float iou_pre(float sum_area,
                                         float g0, float g1, float g2, float g3,
                                         float a0, float a1, float a2, float a3) {
#pragma clang fp contract(off)
    float ltx = fmaxf(g0, a0), lty = fmaxf(g1, a1);
    float rbx = fminf(g2, a2), rby = fminf(g3, a3);
    float wx = fmaxf(rbx - ltx, 0.0f), wy = fmaxf(rby - lty, 0.0f);
    float inter = wx * wy;
    float uni = sum_area - inter;
    return inter * __builtin_amdgcn_rcpf(uni);
}

// Epilogue centerness: exact divides (sign/zero decisions must be exact;
// runs once per anchor, cost negligible).
__device__ __forceinline__ float centerness_fn(float4 an, float4 tb) {
#pragma clang fp contract(off)
    float cx = 0.5f * (an.x + an.z), cy = 0.5f * (an.y + an.w);
    float w = an.z - an.x, h = an.w - an.y;
    float d0 = (cx - tb.x) / w;
    float d1 = (tb.z - cx) / w;
    float d2 = (cy - tb.y) / h;
    float d3 = (tb.w - cy) / h;
    bool inb = (d0 >= 0.0f) && (d1 >= 0.0f) && (d2 >= 0.0f) && (d3 >= 0.0f);
    if (!inb) { d0 = d1 = d2 = d3 = 0.0f; }
    float prod = (fminf(d0, d1) / (fmaxf(d0, d1) + 1e-12f)) *
                 (fminf(d2, d3) / (fmaxf(d2, d3) + 1e-12f));
    return prod > 0.0f ? sqrtf(prod) : 0.0f;
}

// K1: gt-outer / anchors-in-registers inner (wave-uniform gt -> s_load).
// Cross-lane per-g max restructured: in-loop only 2 shfl stages + 1 LDS
// write per g (was 6 dependent shfl stages); one post-loop reduce of the
// 32x64 staging array. blockmax is still the exact max of the same value
// set (max is order-invariant) so k2/k3 semantics are unchanged.
__global__ __launch_bounds__(256) void k1_main(const float* __restrict__ gt,
                                               const float* __restrict__ anchors,
                                               float* __restrict__ out,
                                               float* __restrict__ blockmax,
                                               int A, int B) {
#pragma clang fp contract(off)
    __shared__ float4 s_gt[G];        // for epilogue indexed fetch only
    __shared__ float s_lm[G][64];     // 8 KB staging: per-g, per-4-lane-group max
    const int c = blockIdx.x, b = blockIdx.y, t = threadIdx.x;
    if (t < G) s_gt[t] = ((const float4*)gt)[b * G + t];

    const float4* __restrict__ gt4 = (const float4*)gt;

    float4 an[APT];
    float aa[APT], best[APT];
    int bidx[APT];
    bool valid[APT];
    const int abase = c * CHUNK + t;
#pragma unroll
    for (int k = 0; k < APT; ++k) {
        int a = abase + k * 256;
        valid[k] = (a < A);
        int ac = valid[k] ? a : (A - 1);   // clamp: dup contributions are max-harmless
        an[k] = ((const float4*)anchors)[ac];
        aa[k] = (an[k].z - an[k].x) * (an[k].w - an[k].y);
        best[k] = -1.0f;
        bidx[k] = 0;
    }

    const int lane = t & 63, wid = t >> 6;
    const int wcol = wid * 16 + (lane >> 2);   // this lane-group's staging column
    const bool writer = ((lane & 3) == 0);

#pragma unroll 8
    for (int g = 0; g < G; ++g) {
        const float4 gb = gt4[b * G + g];   // uniform address -> s_load, batched by unroll
        const float ag = (gb.z - gb.x) * (gb.w - gb.y);
        float v[APT];
#pragma unroll
        for (int k = 0; k < APT; ++k) {
            v[k] = iou_pre(ag + aa[k], gb.x, gb.y, gb.z, gb.w,
                           an[k].x, an[k].y, an[k].z, an[k].w);
            if (v[k] > best[k]) { best[k] = v[k]; bidx[k] = g; }  // strict '>': jnp.argmax tie-break
        }
        float lm = fmaxf(fmaxf(v[0], v[1]), fmaxf(v[2], v[3]));
        lm = fmaxf(lm, __shfl_down(lm, 1, 64));
        lm = fmaxf(lm, __shfl_down(lm, 2, 64));
        if (writer) s_lm[g][wcol] = lm;     // groups of 4 lanes reduced
    }
    __syncthreads();

    // Post-reduce: 256 threads cover 32 g x 8 segments; each tree-maxes 8
    // values then 3 shfl stages within its 8-lane group.
    {
        const int g = t >> 3, j = t & 7;
        const float* p = &s_lm[g][j * 8];
        float m = fmaxf(fmaxf(fmaxf(p[0], p[1]), fmaxf(p[2], p[3])),
                        fmaxf(fmaxf(p[4], p[5]), fmaxf(p[6], p[7])));
        m = fmaxf(m, __shfl_down(m, 4, 64));
        m = fmaxf(m, __shfl_down(m, 2, 64));
        m = fmaxf(m, __shfl_down(m, 1, 64));
        if (j == 0) blockmax[(c * B + b) * G + g] = m;
    }

    const size_t BA = (size_t)B * (size_t)A;
    const size_t bA = (size_t)b * (size_t)A;
#pragma unroll
    for (int k = 0; k < APT; ++k) {
        if (!valid[k]) continue;
        const size_t o = bA + (size_t)(abase + k * 256);
        int gl = (best[k] >= 0.7f) ? 1 : ((best[k] >= 0.3f) ? -1 : 0);
        int ol = (best[k] >= 0.3f) ? 1 : ((best[k] >= 0.1f) ? -1 : 0);
        const float4 tb = s_gt[bidx[k]];
        float cen = centerness_fn(an[k], tb);
        if (ol == 0) cen = 0.0f;
        out[o] = (float)gl;
        ((float4*)(out + BA))[o] = tb;
        out[5 * BA + o] = (float)ol;
        out[6 * BA + o] = cen;
    }
}

// K2: hi[bg] = max over C chunks of blockmax. One block (64 thr) per (b,g).
// Bit-exact: fmaxf over the same value set, any order.
__global__ void k2_reduce(const float* __restrict__ blockmax,
                          float* __restrict__ hi, int C, int BG) {
    const int bg = blockIdx.x, t = threadIdx.x;
    float v = 0.0f;
    for (int c = t; c < C; c += 64) v = fmaxf(v, blockmax[c * BG + bg]);
#pragma unroll
    for (int off = 32; off > 0; off >>= 1) v = fmaxf(v, __shfl_down(v, off, 64));
    if (t == 0) hi[bg] = v;
}

// K3 (lite): low-quality patch. A chunk can contain an anchor with
// iou==hi[g] only if its blockmax[g]==hi[g] (iou<=chunkmax<=hi, bit-exact).
// ~85% of blocks exit on mask==0. Flagged blocks rescan ONLY flagged gts
// (popcount ~1-2); matched box is read back from out (k1's argmax), only
// gl/ol/centerness rewritten for v==hi[g] lanes.
__global__ __launch_bounds__(256) void k3_patch(const float* __restrict__ gt,
                                                const float* __restrict__ anchors,
                                                const float* __restrict__ blockmax,
                                                const float* __restrict__ hi,
                                                float* __restrict__ out,
                                                int A, int B) {
#pragma clang fp contract(off)
    __shared__ float4 s_gt[G];
    __shared__ float s_hi[G];
    __shared__ unsigned s_mask;
    const int c = blockIdx.x, b = blockIdx.y, t = threadIdx.x;
    bool fl = false;
    if (t < G) {
        float h = hi[b * G + t];
        s_hi[t] = h;
        s_gt[t] = ((const float4*)gt)[b * G + t];
        fl = (blockmax[(c * B + b) * G + t] == h);
    }
    unsigned long long m = __ballot(fl);
    if (t == 0) s_mask = (unsigned)(m & 0xffffffffull);
    __syncthreads();
    const unsigned mask0 = s_mask;
    if (mask0 == 0) return;

    const size_t BA = (size_t)B * (size_t)A;
    const size_t bA = (size_t)b * (size_t)A;
    const int abase = c * CHUNK + t;

#pragma unroll
    for (int k = 0; k < APT; ++k) {
        const int a = abase + k * 256;
        if (a >= A) continue;
        const float4 an = ((const float4*)anchors)[a];
        const float aa = (an.z - an.x) * (an.w - an.y);
        bool lq = false;
        unsigned mask = mask0;           // block-uniform loop, ~1-2 iterations
        while (mask) {
            const int g = __ffs(mask) - 1;
            mask &= mask - 1;
            const float4 gb = s_gt[g];
            const float ag = (gb.z - gb.x) * (gb.w - gb.y);
            const float v = iou_pre(ag + aa, gb.x, gb.y, gb.z, gb.w,
                                    an.x, an.y, an.z, an.w);
            lq |= (v == s_hi[g]);        // non-flagged g can never hit (v<=blockmax<hi)
        }
        if (lq) {
            const size_t o = bA + (size_t)a;
            const float4 tb = ((const float4*)(out + BA))[o];  // k1's matched box
            const float cen = centerness_fn(an, tb);           // ol=1 -> unmasked
            out[o] = 1.0f;
            out[5 * BA + o] = 1.0f;
            out[6 * BA + o] = cen;
        }
    }
}

extern "C" void kernel_launch(void* const* d_in, const int* in_sizes, int n_in,
                              void* d_out, int out_size, void* d_ws, size_t ws_size,
                              hipStream_t stream) {
    const float* gt = (const float*)d_in[0];       // [B, 32, 4] f32
    const float* anchors = (const float*)d_in[1];  // [A, 4] f32
    float* out = (float*)d_out;

    const int B = in_sizes[0] / (G * 4);
    const int A = in_sizes[1] / 4;
    const int C = (A + CHUNK - 1) / CHUNK;
    const int BG = B * G;

    float* hi = (float*)d_ws;                        // BG floats (k2 fully overwrites)
    float* blockmax = (float*)((char*)d_ws + 1024);  // C*BG floats (~200 KB)

    k1_main<<<dim3(C, B), 256, 0, stream>>>(gt, anchors, out, blockmax, A, B);
    k2_reduce<<<BG, 64, 0, stream>>>(blockmax, hi, C, BG);
    k3_patch<<<dim3(C, B), 256, 0, stream>>>(gt, anchors, blockmax, hi, out, A, B);
}